// Round 15
// baseline (44.717 us; speedup 1.0000x reference)
//
#include <hip/hip_runtime.h>
#include <hip/hip_bf16.h>

// Problem constants: B=8, G=2048, K=32, N=6, C=64; fourier_B is (7,32)
// out: (B, 128, G) float32
//
// Algebraic simplifications (validated):
//  1) up/down == mean_k(knn_f) since e_x is constant over k, so
//     kl_raw = 2*mean_k(sin^5/cos^5(2*pi*x)).
//  2) x = fB . [p, p x n, p.n] is linear in p:
//     x = e0*p0 + e1*p1 + e2*p2 with per-channel e precomputed from fB and n.
//  3) kl/||kl|| is scale-invariant -> the 1/16 mean factor is dropped.
//
// Round 15 (on r14's 19.5us): reduction-free pass2.
//  - pass1 accumulates per-(b,c) Sum(kl^2) via one atomicAdd per lane
//    (register values, no extra LDS/barrier; correctness validated in r12).
//  - pass2 is pure streaming: 1024 blocks, one float4 kl + ll per thread,
//    rn = rsq(ws[row]) -> fma -> store. No reduction, no syncthreads.

#if __has_builtin(__builtin_amdgcn_fractf)
  #define FRACT(x) __builtin_amdgcn_fractf(x)
#else
  #define FRACT(x) ((x) - floorf(x))
#endif

__device__ __forceinline__ float rlanef(float v, int l) {
    return __int_as_float(__builtin_amdgcn_readlane(__float_as_int(v), l));
}

// Full-wave (64-lane) f32 sum via DPP; result returned as wave-uniform.
__device__ __forceinline__ float wave_sum64(float v) {
    float s = v;
    s += __int_as_float(__builtin_amdgcn_update_dpp(
            0, __float_as_int(s), 0x111, 0xf, 0xf, true));  // row_shr:1
    s += __int_as_float(__builtin_amdgcn_update_dpp(
            0, __float_as_int(s), 0x112, 0xf, 0xf, true));  // row_shr:2
    s += __int_as_float(__builtin_amdgcn_update_dpp(
            0, __float_as_int(s), 0x114, 0xf, 0xf, true));  // row_shr:4
    s += __int_as_float(__builtin_amdgcn_update_dpp(
            0, __float_as_int(s), 0x118, 0xf, 0xf, true));  // row_shr:8
    s += __int_as_float(__builtin_amdgcn_update_dpp(
            0, __float_as_int(s), 0x142, 0xf, 0xf, true));  // row_bcast:15
    s += __int_as_float(__builtin_amdgcn_update_dpp(
            0, __float_as_int(s), 0x143, 0xf, 0xf, true));  // row_bcast:31
    return rlanef(s, 63);
}

__global__ __launch_bounds__(256, 8) void line_pass1(
    const float* __restrict__ lc_x,     // (B,G,64)
    const float* __restrict__ knn_x,    // (B,G,32,6)
    const float* __restrict__ fB,       // (7,32)
    float* __restrict__ out,            // (B,128,G)
    float* __restrict__ ws)             // 512 floats, zeroed per launch
{
    const int wave = threadIdx.x >> 6;
    const int lane = threadIdx.x & 63;
    const int half = lane >> 5;                 // staging: which bg; loop: k parity
    const int jj   = lane & 31;                 // channel, and gather-k
    // bijective XCD swizzle: 2048 blocks, 8 XCDs, 256 blocks each
    const int sbid = (blockIdx.x & 7) * 256 + (blockIdx.x >> 3);
    const int bg0  = sbid * 8;                  // 8 consecutive bg per block
    const int b    = bg0 >> 11;
    const int g0   = bg0 & 2047;                // 8-aligned, never crosses b

    __shared__ __align__(16) float4 pbuf[4][2][32];  // [wave][bg_i][k] packed p
    __shared__ float klbuf[128][9];                  // [channel][col], odd pad

    // fourier_B column for this lane's channel
    const float fb0 = fB[0*32 + jj];
    const float fb1 = fB[1*32 + jj];
    const float fb2 = fB[2*32 + jj];
    const float fb3 = fB[3*32 + jj];
    const float fb4 = fB[4*32 + jj];
    const float fb5 = fB[5*32 + jj];
    const float fb6 = fB[6*32 + jj];

    // ---- global loads issued up front (coalesced lc; strided p gather)
    const int bgw = bg0 + wave * 2;
    const float myv0 = lc_x[(size_t)bgw * 64 + lane];
    const float myv1 = lc_x[(size_t)(bgw + 1) * 64 + lane];
    {
        const float* kp = knn_x + (size_t)(bgw + half) * 192 + jj * 6;
        pbuf[wave][half][jj] = make_float4(kp[3], kp[4], kp[5], 0.0f);
    }
    // producer and consumer are the same wave -> wave-local wait, no barrier
    asm volatile("s_waitcnt lgkmcnt(0)" ::: "memory");

    float kv[2];                                // this lane's kl values (2 cols)
    #pragma unroll
    for (int i = 0; i < 2; ++i) {
        const int col = wave * 2 + i;
        const float myv = (i == 0) ? myv0 : myv1;

        // lc_normal = lc[3:6] via register broadcast (VALU, no LDS)
        const float n0 = rlanef(myv, 3);
        const float n1 = rlanef(myv, 4);
        const float n2 = rlanef(myv, 5);

        // lc_line: normalize over C=64 (DPP reduce, VALU-pipe only)
        const float ssum = wave_sum64(myv * myv);
        klbuf[64 + lane][col] = myv * __builtin_amdgcn_rsqf(ssum);

        // effective projection vector: x = e0*p0 + e1*p1 + e2*p2
        const float e0 = fmaf(fb6, n0, fmaf(fb5,  n1, fmaf(fb4, -n2, fb0)));
        const float e1 = fmaf(fb6, n1, fmaf(fb5, -n0, fmaf(fb3,  n2, fb1)));
        const float e2 = fmaf(fb6, n2, fmaf(fb4,  n0, fmaf(fb3, -n1, fb2)));

        float accS0 = 0.f, accS1 = 0.f, accC0 = 0.f, accC1 = 0.f;
        const float4* myk = &pbuf[wave][i][half];       // k = 2*t + half
        #pragma unroll
        for (int t = 0; t < 16; ++t) {
            const float4 p = myk[2 * t];                // ONE uniform b128/iter
            const float x  = fmaf(e2, p.z, fmaf(e1, p.y, e0 * p.x));
            const float ts = FRACT(x);                  // revolutions [0,1)
            const float s  = __builtin_amdgcn_sinf(ts); // sin(2*pi*x)
            const float cq = __builtin_amdgcn_cosf(ts); // cos(2*pi*x)
            const float s2 = s * s,   s4 = s2 * s2;
            const float q2 = cq * cq, q4 = q2 * q2;
            if (t & 1) { accS1 = fmaf(s4, s, accS1); accC1 = fmaf(q4, cq, accC1); }
            else       { accS0 = fmaf(s4, s, accS0); accC0 = fmaf(q4, cq, accC0); }
        }
        // merge even-k / odd-k halves across the lane32 boundary
        const float aS = accS0 + accS1;
        const float aC = accC0 + accC1;
        const float totS = aS + __shfl_xor(aS, 32, 64);
        const float totC = aC + __shfl_xor(aC, 32, 64);
        kv[i] = (half ? totC : totS);       // unscaled: 1/16 cancels in the norm
        klbuf[lane][col] = kv[i];
    }

    // per-(b,channel) Sum(kl^2) partial: one atomic per lane, fire-and-forget
    atomicAdd(&ws[b * 64 + lane], fmaf(kv[0], kv[0], kv[1] * kv[1]));

    __syncthreads();

    // cooperative coalesced store: thread t -> row c=t>>1, cols (t&1)*4..+3
    const int c  = threadIdx.x >> 1;
    const int j0 = (threadIdx.x & 1) * 4;
    const float4 o = make_float4(klbuf[c][j0], klbuf[c][j0+1],
                                 klbuf[c][j0+2], klbuf[c][j0+3]);
    *(float4*)(out + ((size_t)b * 128 + c) * 2048 + g0 + j0) = o;
}

// Pure streaming normalize: one float4 of kl + matching ll per thread.
__global__ __launch_bounds__(256) void line_pass2(
    float* __restrict__ out, const float* __restrict__ ws)
{
    const int i   = blockIdx.x * 256 + threadIdx.x;   // 0..262143 float4s of kl
    const int row = i >> 9;                           // 0..511 = b*64 + c
    const int b   = row >> 6;
    const int c   = row & 63;
    const int q   = i & 511;                          // float4 index within row

    float4*       kl = (float4*)(out + ((size_t)b * 128 + c) * 2048) + q;
    const float4* ll = (const float4*)(out + ((size_t)b * 128 + 64 + c) * 2048) + q;

    const float rn = __builtin_amdgcn_rsqf(ws[row]);
    const float4 v = *kl;
    const float4 l = *ll;
    *kl = make_float4(fmaf(v.x, rn, -l.x), fmaf(v.y, rn, -l.y),
                      fmaf(v.z, rn, -l.z), fmaf(v.w, rn, -l.w));
}

extern "C" void kernel_launch(void* const* d_in, const int* in_sizes, int n_in,
                              void* d_out, int out_size, void* d_ws, size_t ws_size,
                              hipStream_t stream) {
    const float* lc_x  = (const float*)d_in[0];   // 8*2048*64
    const float* knn_x = (const float*)d_in[1];   // 8*2048*32*6
    const float* fB    = (const float*)d_in[2];   // 7*32
    float* out = (float*)d_out;                   // 8*128*2048
    float* ws  = (float*)d_ws;                    // >= 512 floats

    hipMemsetAsync(d_ws, 0, 512 * sizeof(float), stream);
    line_pass1<<<2048, 256, 0, stream>>>(lc_x, knn_x, fB, out, ws);
    line_pass2<<<1024, 256, 0, stream>>>(out, ws);
}

// Round 17
// 19.344 us; speedup vs baseline: 2.3118x; 2.3118x over previous
//
#include <hip/hip_runtime.h>
#include <hip/hip_bf16.h>

// Problem constants: B=8, G=2048, K=32, N=6, C=64; fourier_B is (7,32)
// out: (B, 128, G) float32
//
// Algebraic simplifications (validated):
//  1) up/down == mean_k(knn_f) since e_x is constant over k, so
//     kl_raw = 2*mean_k(sin^5/cos^5(2*pi*x)).
//  2) x = fB . [p, p x n, p.n] is linear in p:
//     x = e0*p0 + e1*p1 + e2*p2 with per-channel e precomputed from fB and n.
//  3) kl/||kl|| is scale-invariant -> 1/16 mean factor dropped (r15 validated).
//
// Round 17 = r16 with the OOB dwordx4 gather reverted to 3 scalar loads
// (r16 crashed: jj=31 record read 1 float past the last knn row).
//  - norms + e-vectors hoisted BEFORE the lgkmcnt wait (overlap ds-write drain
//    and lc HBM latency with VALU).
//  - fused dual-bg t-loop: both bg bodies in one scheduling region (2x ILP vs
//    the ~120cyc LDS broadcast latency).
//  - packed {sin,cos} power chain via ext_vector(2) -> v_pk_mul/v_pk_fma.

#if __has_builtin(__builtin_amdgcn_fractf)
  #define FRACT(x) __builtin_amdgcn_fractf(x)
#else
  #define FRACT(x) ((x) - floorf(x))
#endif

typedef float f2v __attribute__((ext_vector_type(2)));

__device__ __forceinline__ float rlanef(float v, int l) {
    return __int_as_float(__builtin_amdgcn_readlane(__float_as_int(v), l));
}

// Full-wave (64-lane) f32 sum via DPP; result wave-uniform.
__device__ __forceinline__ float wave_sum64(float v) {
    float s = v;
    s += __int_as_float(__builtin_amdgcn_update_dpp(
            0, __float_as_int(s), 0x111, 0xf, 0xf, true));  // row_shr:1
    s += __int_as_float(__builtin_amdgcn_update_dpp(
            0, __float_as_int(s), 0x112, 0xf, 0xf, true));  // row_shr:2
    s += __int_as_float(__builtin_amdgcn_update_dpp(
            0, __float_as_int(s), 0x114, 0xf, 0xf, true));  // row_shr:4
    s += __int_as_float(__builtin_amdgcn_update_dpp(
            0, __float_as_int(s), 0x118, 0xf, 0xf, true));  // row_shr:8
    s += __int_as_float(__builtin_amdgcn_update_dpp(
            0, __float_as_int(s), 0x142, 0xf, 0xf, true));  // row_bcast:15
    s += __int_as_float(__builtin_amdgcn_update_dpp(
            0, __float_as_int(s), 0x143, 0xf, 0xf, true));  // row_bcast:31
    return rlanef(s, 63);
}

__global__ __launch_bounds__(256, 8) void line_pass1(
    const float* __restrict__ lc_x,     // (B,G,64)
    const float* __restrict__ knn_x,    // (B,G,32,6)
    const float* __restrict__ fB,       // (7,32)
    float* __restrict__ out)            // (B,128,G)
{
    const int wave = threadIdx.x >> 6;
    const int lane = threadIdx.x & 63;
    const int half = lane >> 5;                 // staging: which bg; loop: k parity
    const int jj   = lane & 31;                 // channel, and gather-k
    // bijective XCD swizzle: 2048 blocks, 8 XCDs, 256 blocks each
    const int sbid = (blockIdx.x & 7) * 256 + (blockIdx.x >> 3);
    const int bg0  = sbid * 8;                  // 8 consecutive bg per block
    const int b    = bg0 >> 11;
    const int g0   = bg0 & 2047;                // 8-aligned, never crosses b

    __shared__ __align__(16) float4 pbuf[4][2][32];  // [wave][bg_i][k] packed p
    __shared__ float klbuf[128][9];                  // [channel][col], odd pad

    // fourier_B column for this lane's channel
    const float fb0 = fB[0*32 + jj];
    const float fb1 = fB[1*32 + jj];
    const float fb2 = fB[2*32 + jj];
    const float fb3 = fB[3*32 + jj];
    const float fb4 = fB[4*32 + jj];
    const float fb5 = fB[5*32 + jj];
    const float fb6 = fB[6*32 + jj];

    // ---- global loads issued up front (coalesced lc; 3-scalar p gather)
    const int bgw = bg0 + wave * 2;
    const float myv0 = lc_x[(size_t)bgw * 64 + lane];
    const float myv1 = lc_x[(size_t)(bgw + 1) * 64 + lane];
    {
        const float* kp = knn_x + (size_t)(bgw + half) * 192 + jj * 6;
        pbuf[wave][half][jj] = make_float4(kp[3], kp[4], kp[5], 0.0f);
    }

    // ---- norms + e-vectors for BOTH bg before the LDS wait (overlap drain)
    const float nA0 = rlanef(myv0, 3), nA1 = rlanef(myv0, 4), nA2 = rlanef(myv0, 5);
    const float nB0 = rlanef(myv1, 3), nB1 = rlanef(myv1, 4), nB2 = rlanef(myv1, 5);

    const float ssA = wave_sum64(myv0 * myv0);
    const float ssB = wave_sum64(myv1 * myv1);
    klbuf[64 + lane][wave * 2 + 0] = myv0 * __builtin_amdgcn_rsqf(ssA);
    klbuf[64 + lane][wave * 2 + 1] = myv1 * __builtin_amdgcn_rsqf(ssB);

    const float e0A = fmaf(fb6, nA0, fmaf(fb5,  nA1, fmaf(fb4, -nA2, fb0)));
    const float e1A = fmaf(fb6, nA1, fmaf(fb5, -nA0, fmaf(fb3,  nA2, fb1)));
    const float e2A = fmaf(fb6, nA2, fmaf(fb4,  nA0, fmaf(fb3, -nA1, fb2)));
    const float e0B = fmaf(fb6, nB0, fmaf(fb5,  nB1, fmaf(fb4, -nB2, fb0)));
    const float e1B = fmaf(fb6, nB1, fmaf(fb5, -nB0, fmaf(fb3,  nB2, fb1)));
    const float e2B = fmaf(fb6, nB2, fmaf(fb4,  nB0, fmaf(fb3, -nB1, fb2)));

    // producer and consumer are the same wave -> wave-local wait, no barrier
    asm volatile("s_waitcnt lgkmcnt(0)" ::: "memory");

    // ---- fused dual-bg k-loop: k = 2*t + half for each bg
    f2v accA0 = {0.f, 0.f}, accA1 = {0.f, 0.f};
    f2v accB0 = {0.f, 0.f}, accB1 = {0.f, 0.f};
    const float4* pa = &pbuf[wave][0][half];
    const float4* pb = &pbuf[wave][1][half];
    #pragma unroll
    for (int t = 0; t < 16; ++t) {
        const float4 p = pa[2 * t];                 // uniform b128 broadcast
        const float4 q = pb[2 * t];
        const float xA = fmaf(e2A, p.z, fmaf(e1A, p.y, e0A * p.x));
        const float xB = fmaf(e2B, q.z, fmaf(e1B, q.y, e0B * q.x));
        const float tA = FRACT(xA);
        const float tB = FRACT(xB);
        f2v scA; scA.x = __builtin_amdgcn_sinf(tA); scA.y = __builtin_amdgcn_cosf(tA);
        f2v scB; scB.x = __builtin_amdgcn_sinf(tB); scB.y = __builtin_amdgcn_cosf(tB);
        const f2v sA2 = scA * scA, sB2 = scB * scB;     // v_pk_mul_f32
        const f2v sA4 = sA2 * sA2, sB4 = sB2 * sB2;
        if (t & 1) { accA1 += sA4 * scA; accB1 += sB4 * scB; }  // v_pk_fma_f32
        else       { accA0 += sA4 * scA; accB0 += sB4 * scB; }
    }
    const f2v aA = accA0 + accA1;       // {sin-sum, cos-sum} for this k-parity
    const f2v aB = accB0 + accB1;

    // merge even-k / odd-k halves across the lane32 boundary
    const float sA = aA.x + __shfl_xor(aA.x, 32, 64);
    const float cA = aA.y + __shfl_xor(aA.y, 32, 64);
    const float sB = aB.x + __shfl_xor(aB.x, 32, 64);
    const float cB = aB.y + __shfl_xor(aB.y, 32, 64);
    klbuf[lane][wave * 2 + 0] = half ? cA : sA;   // unscaled (norm cancels)
    klbuf[lane][wave * 2 + 1] = half ? cB : sB;

    __syncthreads();

    // cooperative coalesced store: thread t -> row c=t>>1, cols (t&1)*4..+3
    const int c  = threadIdx.x >> 1;
    const int j0 = (threadIdx.x & 1) * 4;
    const float4 o = make_float4(klbuf[c][j0], klbuf[c][j0+1],
                                 klbuf[c][j0+2], klbuf[c][j0+3]);
    *(float4*)(out + ((size_t)b * 128 + c) * 2048 + g0 + j0) = o;
}

__global__ __launch_bounds__(256) void line_pass2(float* __restrict__ out)
{
    const int b = blockIdx.x >> 6;   // 0..7
    const int c = blockIdx.x & 63;   // 0..63
    float4*       kl = (float4*)(out + ((size_t)b * 128 + c) * 2048);
    const float4* ll = (const float4*)(out + ((size_t)b * 128 + 64 + c) * 2048);
    const int t = threadIdx.x;

    // issue ALL loads before the reduction so HBM latencies overlap
    const float4 v0 = kl[t];
    const float4 v1 = kl[t + 256];
    const float4 l0 = ll[t];
    const float4 l1 = ll[t + 256];

    float ss = v0.x*v0.x + v0.y*v0.y + v0.z*v0.z + v0.w*v0.w
             + v1.x*v1.x + v1.y*v1.y + v1.z*v1.z + v1.w*v1.w;
    #pragma unroll
    for (int off = 32; off; off >>= 1) ss += __shfl_xor(ss, off, 64);

    __shared__ float wsum[4];
    if ((t & 63) == 0) wsum[t >> 6] = ss;
    __syncthreads();
    const float tot = wsum[0] + wsum[1] + wsum[2] + wsum[3];
    const float rn  = __builtin_amdgcn_rsqf(tot);

    kl[t]       = make_float4(fmaf(v0.x, rn, -l0.x), fmaf(v0.y, rn, -l0.y),
                              fmaf(v0.z, rn, -l0.z), fmaf(v0.w, rn, -l0.w));
    kl[t + 256] = make_float4(fmaf(v1.x, rn, -l1.x), fmaf(v1.y, rn, -l1.y),
                              fmaf(v1.z, rn, -l1.z), fmaf(v1.w, rn, -l1.w));
}

extern "C" void kernel_launch(void* const* d_in, const int* in_sizes, int n_in,
                              void* d_out, int out_size, void* d_ws, size_t ws_size,
                              hipStream_t stream) {
    const float* lc_x  = (const float*)d_in[0];   // 8*2048*64
    const float* knn_x = (const float*)d_in[1];   // 8*2048*32*6
    const float* fB    = (const float*)d_in[2];   // 7*32
    float* out = (float*)d_out;                   // 8*128*2048

    line_pass1<<<2048, 256, 0, stream>>>(lc_x, knn_x, fB, out);
    line_pass2<<<512, 256, 0, stream>>>(out);
}